// Round 4
// baseline (173.847 us; speedup 1.0000x reference)
//
#include <hip/hip_runtime.h>

// LSTM_WP: B=4096 batch-1 LSTMs, T=H=128, input_size=1, fused MFMA-f16 recurrence.
// Round 4: round-3 counters showed VGPR_Count=64 -> the 64-VGPR W_hh fragment
// array was STILL reloaded from L2 every step (4.2 GB / 122 us = 34 TB/s = the
// L2 ceiling; kernel was L2-BW-bound). The pre-loop asm pin failed because
// read-only loads are rematerializable. Fix: empty asm "+v" black-box on every
// wf fragment INSIDE the t-loop -> values are asm-modified each iteration and
// must stay register-resident. Success signal: VGPR_Count >= ~140.

#define H   128
#define T   128
#define MB  16          // batches per block
#define BLOCK 512
#define HSTRIDE 136     // f16 per h row: 272 B = 17*16 -> b128-aligned, 2-way banks (free)
#define XSTRIDE 20      // f32 per xs row: 80 B, 16B-aligned b128 reads, conflict-free

typedef _Float16 f16x8 __attribute__((ext_vector_type(8)));
typedef float    f32x4 __attribute__((ext_vector_type(4)));

// ---------------- prep: W_hh f32 [512][128] -> f16 fragment-contiguous ----------------
// layout: idx(ct,g,kc,q,l15) = (((ct*4+g)*4+kc)*4+q)*16+l15, 8 f16 each (16 B).
__global__ void prep_whh_kernel(const float* __restrict__ W_hh, _Float16* __restrict__ wfrag)
{
    int idx = blockIdx.x * blockDim.x + threadIdx.x;     // 0..8191
    int l15 =  idx        & 15;
    int q   = (idx >> 4)  & 3;
    int kc  = (idx >> 6)  & 3;
    int g   = (idx >> 8)  & 3;
    int ct  = (idx >> 10) & 7;
    int n  = g * H + ct * 16 + l15;                      // gate row in [0,512)
    int k0 = kc * 32 + q * 8;
    const float* src = W_hh + (size_t)n * H + k0;
    f16x8 f;
    #pragma unroll
    for (int i = 0; i < 8; ++i) f[i] = (_Float16)src[i];
    *(f16x8*)(wfrag + (size_t)idx * 8) = f;
}

__device__ __forceinline__ float frcp(float v) { return __builtin_amdgcn_rcpf(v); }

__launch_bounds__(BLOCK, 2)
__global__ void lstm_fused_kernel(const float* __restrict__ x,
                                  const float* __restrict__ W_ih,
                                  const _Float16* __restrict__ wfrag,
                                  const float* __restrict__ b_ih,
                                  const float* __restrict__ b_hh,
                                  const float* __restrict__ fc_W,
                                  const float* __restrict__ fc_b,
                                  float* __restrict__ out)
{
    __shared__ __align__(16) float xs[T + 1][XSTRIDE];           // +1 row: prefetch overrun pad
    __shared__ __align__(16) _Float16 hbuf[2][MB][HSTRIDE];      // 8.5 KB h double-buffer

    const int tid  = threadIdx.x;
    const int wave = tid >> 6;          // column tile 0..7
    const int lane = tid & 63;
    const int l15  = lane & 15;
    const int q    = lane >> 4;         // 0..3
    const int jcol = wave * 16 + l15;   // hidden column 0..127

    // ---- stage x: [b][t] global -> xs[t][b] (coalesced reads; one-time) ----
    {
        const int t0 = tid & 127;
        const int b0 = (tid >> 7) * 4;  // 0,4,8,12
        const float* xb = x + (size_t)blockIdx.x * (MB * T);
        #pragma unroll
        for (int bb = 0; bb < 4; ++bb)
            xs[t0][b0 + bb] = xb[(b0 + bb) * T + t0];
    }
    for (int i = tid; i < MB * HSTRIDE; i += BLOCK)              // h0 = 0
        (&hbuf[0][0][0])[i] = (_Float16)0.0f;

    // ---- load pre-converted W_hh fragments (f16, lane-coalesced 16 B each) ----
    f16x8 wf[4][4];                     // [gate][kc], 64 VGPRs, register-pinned below
    {
        const _Float16* wbase = wfrag + (size_t)wave * (4 * 4 * 4 * 16 * 8);
        #pragma unroll
        for (int g = 0; g < 4; ++g)
            #pragma unroll
            for (int kc = 0; kc < 4; ++kc)
                wf[g][kc] = *(const f16x8*)(wbase + ((((g * 4 + kc) * 4 + q) * 16 + l15) * 8));
    }

    float wih[4], bias[4];
    #pragma unroll
    for (int g = 0; g < 4; ++g) {
        const int n = g * H + jcol;
        wih[g]  = W_ih[n];
        bias[g] = b_ih[n] + b_hh[n];
    }

    float c0[4] = {0.f, 0.f, 0.f, 0.f};

    __syncthreads();

    // preact init for t=0 (x_0*W_ih + b_ih + b_hh), rows b = q*4+r
    f32x4 initv[4];
    {
        float4 xl = *(const float4*)&xs[0][q * 4];
        #pragma unroll
        for (int g = 0; g < 4; ++g) {
            initv[g][0] = fmaf(xl.x, wih[g], bias[g]);
            initv[g][1] = fmaf(xl.y, wih[g], bias[g]);
            initv[g][2] = fmaf(xl.z, wih[g], bias[g]);
            initv[g][3] = fmaf(xl.w, wih[g], bias[g]);
        }
    }

    for (int t = 0; t < T; ++t) {
        // REGISTER PIN (the round-4 fix): asm-"modify" each weight fragment every
        // iteration -> not rematerializable, must live in VGPRs across the loop.
        #pragma unroll
        for (int g = 0; g < 4; ++g)
            #pragma unroll
            for (int kc = 0; kc < 4; ++kc)
                asm volatile("" : "+v"(wf[g][kc]));

        const int rb = t & 1;
        const int wb = rb ^ 1;

        // A-fragments: m(batch)=l15, k = kc*32 + q*8 + i
        f16x8 af[4];
        #pragma unroll
        for (int kc = 0; kc < 4; ++kc)
            af[kc] = *(const f16x8*)&hbuf[rb][l15][kc * 32 + q * 8];

        // gates = init + h @ W_hh^T; kc-outer g-inner -> 4 independent acc chains
        f32x4 acc[4];
        #pragma unroll
        for (int g = 0; g < 4; ++g)
            acc[g] = __builtin_amdgcn_mfma_f32_16x16x32_f16(af[0], wf[g][0], initv[g], 0, 0, 0);
        #pragma unroll
        for (int kc = 1; kc < 4; ++kc)
            #pragma unroll
            for (int g = 0; g < 4; ++g)
                acc[g] = __builtin_amdgcn_mfma_f32_16x16x32_f16(af[kc], wf[g][kc], acc[g], 0, 0, 0);

        // next step's init: independent of MFMA results -> issues in the MFMA shadow
        {
            float4 xl = *(const float4*)&xs[t + 1][q * 4];
            #pragma unroll
            for (int g = 0; g < 4; ++g) {
                initv[g][0] = fmaf(xl.x, wih[g], bias[g]);
                initv[g][1] = fmaf(xl.y, wih[g], bias[g]);
                initv[g][2] = fmaf(xl.z, wih[g], bias[g]);
                initv[g][3] = fmaf(xl.w, wih[g], bias[g]);
            }
        }

        // fused-rcp elementwise: 5 exp + 2 rcp per gate-set
        #pragma unroll
        for (int r = 0; r < 4; ++r) {
            const int b = q * 4 + r;
            float ai = acc[0][r], afv = acc[1][r], ag = acc[2][r], ao = acc[3][r];
            float Ei = __expf(-ai);                  // sigmoid_i = 1/(1+Ei)
            float Ef = __expf(-afv);                 // sigmoid_f = 1/(1+Ef)
            float Eg = __expf(2.0f * ag);            // tanh_g = (Eg-1)/(Eg+1)
            float u  = 1.0f + Ei;
            float v  = 1.0f + Ef;
            float w  = 1.0f + Eg;
            float wm = Eg - 1.0f;
            float uw = u * w;
            // c' = c/v + wm/(u*w)  ->  [c*u*w + wm*v] / (v*u*w), ONE rcp
            float cn = fmaf(c0[r], uw, wm * v) * frcp(v * uw);
            c0[r] = cn;
            float Eo = __expf(-ao);                  // sigmoid_o = 1/(1+Eo)
            float Ec = __expf(2.0f * cn);            // tanh(c') = (Ec-1)/(Ec+1)
            float hv = (Ec - 1.0f) * frcp((Ec + 1.0f) * (1.0f + Eo));
            hbuf[wb][b][jcol] = (_Float16)hv;
        }
        __syncthreads();
    }

    // ---- epilogue: out[b] = fc_b + sum_j fc_W[j] * hT[b][j]  (hT in hbuf[0]) ----
    if (tid < 256) {
        const int b    = tid >> 4;
        const int part = tid & 15;
        const _Float16* hrow = &hbuf[0][b][0];
        float s = 0.0f;
        #pragma unroll
        for (int i = 0; i < 8; ++i) {
            const int j = part * 8 + i;
            s += fc_W[j] * (float)hrow[j];
        }
        s += __shfl_xor(s, 8, 16);
        s += __shfl_xor(s, 4, 16);
        s += __shfl_xor(s, 2, 16);
        s += __shfl_xor(s, 1, 16);
        if (part == 0)
            out[blockIdx.x * MB + b] = s + fc_b[0];
    }
}

extern "C" void kernel_launch(void* const* d_in, const int* in_sizes, int n_in,
                              void* d_out, int out_size, void* d_ws, size_t ws_size,
                              hipStream_t stream)
{
    const float* x    = (const float*)d_in[0];
    const float* W_ih = (const float*)d_in[1];
    const float* W_hh = (const float*)d_in[2];
    const float* b_ih = (const float*)d_in[3];
    const float* b_hh = (const float*)d_in[4];
    const float* fc_W = (const float*)d_in[5];
    const float* fc_b = (const float*)d_in[6];
    float* out = (float*)d_out;

    _Float16* wfrag = (_Float16*)d_ws;     // 64K f16 = 128 KB fragment-ordered W_hh

    hipLaunchKernelGGL(prep_whh_kernel, dim3(32), dim3(256), 0, stream, W_hh, wfrag);

    const int B = in_sizes[0] / H;         // 4096 chunks
    dim3 grid(B / MB);                     // 256 blocks -> 1 per CU
    dim3 block(BLOCK);                     // 8 waves -> 2 per SIMD
    hipLaunchKernelGGL(lstm_fused_kernel, grid, block, 0, stream,
                       x, W_ih, wfrag, b_ih, b_hh, fc_W, fc_b, out);
}